// Round 13
// baseline (477.048 us; speedup 1.0000x reference)
//
#include <hip/hip_runtime.h>
#include <hip/hip_fp16.h>

typedef __attribute__((ext_vector_type(8))) short bf16x8;
typedef __attribute__((ext_vector_type(4))) float f32x4;

__device__ __forceinline__ f32x4 mfma16(bf16x8 a, bf16x8 b, f32x4 c) {
    return __builtin_amdgcn_mfma_f32_16x16x32_bf16(a, b, c, 0, 0, 0);
}

__device__ __forceinline__ unsigned short bf16_rte(float f) {
    unsigned int u = __float_as_uint(f);
    unsigned int r = (u + 0x7FFFu + ((u >> 16) & 1u)) >> 16;
    return (unsigned short)r;
}
__device__ __forceinline__ float bf16_f(unsigned short h) {
    return __uint_as_float(((unsigned int)h) << 16);
}

// split 8 fp16 values (bit-packed) into bf16 hi/lo (exact)
__device__ __forceinline__ void split8h(bf16x8 raw, bf16x8& hi, bf16x8& lo) {
#pragma unroll
    for (int j = 0; j < 8; ++j) {
        float f = __half2float(__ushort_as_half((unsigned short)raw[j]));
        unsigned short h = bf16_rte(f);
        hi[j] = (short)h;
        lo[j] = (short)bf16_rte(f - bf16_f(h));
    }
}

__device__ __forceinline__ void acc8(uint4 r, float4& A0, float4& A1) {
    float2 v0 = __half22float2(*(const __half2*)&r.x);
    float2 v1 = __half22float2(*(const __half2*)&r.y);
    float2 v2 = __half22float2(*(const __half2*)&r.z);
    float2 v3 = __half22float2(*(const __half2*)&r.w);
    A0.x += v0.x; A0.y += v0.y; A0.z += v1.x; A0.w += v1.y;
    A1.x += v2.x; A1.y += v2.y; A1.z += v3.x; A1.w += v3.y;
}

__device__ __forceinline__ void acc4(uint2 r, float4& A) {
    float2 v0 = __half22float2(*(const __half2*)&r.x);
    float2 v1 = __half22float2(*(const __half2*)&r.y);
    A.x += v0.x; A.y += v0.y; A.z += v1.x; A.w += v1.y;
}

#define MAXNB 1024

// ---------------- fused prep: wconv + xconv + per-node degree count ---------
// deg[] pre-zeroed by memset. Direct counting sort (r12->r13): the bucketed
// pairs round-trip (bscatter+build, ~3.5 E-passes + 19 MB pairs traffic) is
// replaced by {degcount, bucket-sum, bucket-scan, node-scan, scatter} = 2
// E-passes. deg histogram = 400 KB, L2-resident; ~16 collisions/counter.
__global__ __launch_bounds__(256) void k_prep(
    const float* __restrict__ Wl1, const float* __restrict__ Wr1,
    const float* __restrict__ Wl2, const float* __restrict__ Wr2,
    unsigned short* __restrict__ w1ah, unsigned short* __restrict__ w1al,
    unsigned short* __restrict__ w1bh, unsigned short* __restrict__ w1bl,
    unsigned short* __restrict__ w2ah, unsigned short* __restrict__ w2al,
    unsigned short* __restrict__ w2bh, unsigned short* __restrict__ w2bl,
    const float* __restrict__ x, unsigned short* __restrict__ x16,
    const int* __restrict__ dst, int* __restrict__ deg,
    int E, int chunk, int xb, int total8) {
    int b = blockIdx.x;
    int t = threadIdx.x;
    if (b < 192) {  // weight conversion: 64+64+32+32 blocks
        const float* W;
        unsigned short *hi, *lo;
        int F, e;
        if (b < 64)       { W = Wl1; hi = w1ah; lo = w1al; F = 128; e = b * 256 + t; }
        else if (b < 128) { W = Wr1; hi = w1bh; lo = w1bl; F = 128; e = (b - 64) * 256 + t; }
        else if (b < 160) { W = Wl2; hi = w2ah; lo = w2al; F = 64;  e = (b - 128) * 256 + t; }
        else              { W = Wr2; hi = w2bh; lo = w2bl; F = 64;  e = (b - 160) * 256 + t; }
        if (e >= 128 * F) return;
        int col = e >> 7, k = e & 127;
        float v = W[(size_t)k * F + col];
        unsigned short h = bf16_rte(v);
        hi[e] = h;
        lo[e] = bf16_rte(v - bf16_f(h));
    } else if (b < 192 + xb) {  // x fp32 -> fp16 table
        int i = (b - 192) * 256 + t;
        if (i >= total8) return;
        const float4* xp = (const float4*)x + (size_t)i * 2;
        float4 a = xp[0], bb = xp[1];
        bf16x8 o;
        o[0] = (short)__half_as_ushort(__float2half_rn(a.x));
        o[1] = (short)__half_as_ushort(__float2half_rn(a.y));
        o[2] = (short)__half_as_ushort(__float2half_rn(a.z));
        o[3] = (short)__half_as_ushort(__float2half_rn(a.w));
        o[4] = (short)__half_as_ushort(__float2half_rn(bb.x));
        o[5] = (short)__half_as_ushort(__float2half_rn(bb.y));
        o[6] = (short)__half_as_ushort(__float2half_rn(bb.z));
        o[7] = (short)__half_as_ushort(__float2half_rn(bb.w));
        *(bf16x8*)&x16[(size_t)i * 8] = o;
    } else {  // per-node degree count
        int cb = b - 192 - xb;
        int base = cb * chunk;
        int end = min(base + chunk, E);
        for (int i = base + t; i < end; i += 256)
            atomicAdd(&deg[dst[i]], 1);
    }
}

// ---------------- direct CSR: bucket sums -> scan -> node scan -> scatter ---

__global__ __launch_bounds__(128) void k_bsum(
    const int* __restrict__ deg, int* __restrict__ bcnt, int n) {
    __shared__ int sh[128];
    int b = blockIdx.x, t = threadIdx.x;
    int node = b * 128 + t;
    sh[t] = (node < n) ? deg[node] : 0;
    __syncthreads();
    for (int off = 64; off > 0; off >>= 1) {
        if (t < off) sh[t] += sh[t + off];
        __syncthreads();
    }
    if (t == 0) bcnt[b] = sh[0];
}

__global__ void k_bscan(const int* __restrict__ bcnt, int* __restrict__ boff,
                        int nb) {
    __shared__ int sh[1024];
    int t = threadIdx.x;
    int v = (t < nb) ? bcnt[t] : 0;
    sh[t] = v;
    __syncthreads();
    for (int off = 1; off < 1024; off <<= 1) {
        int u = (t >= off) ? sh[t - off] : 0;
        __syncthreads();
        sh[t] += u;
        __syncthreads();
    }
    if (t < nb) boff[t] = sh[t] - v;
}

__global__ __launch_bounds__(128) void k_nscan(
    const int* __restrict__ deg, const int* __restrict__ boff,
    int* __restrict__ start, int* __restrict__ cur, int n) {
    __shared__ int sh[128];
    int b = blockIdx.x, t = threadIdx.x;
    int node = b * 128 + t;
    int v = (node < n) ? deg[node] : 0;
    sh[t] = v;
    __syncthreads();
    for (int off = 1; off < 128; off <<= 1) {
        int u = (t >= off) ? sh[t - off] : 0;
        __syncthreads();
        sh[t] += u;
        __syncthreads();
    }
    if (node < n) {
        int ex = sh[t] - v + boff[b];
        start[node] = ex;
        cur[node] = ex;
    }
}

__global__ __launch_bounds__(256) void k_scatter(
    const int* __restrict__ src, const int* __restrict__ dst,
    int* __restrict__ cur, int* __restrict__ csr, int E) {
    int i0 = blockIdx.x * 256 + threadIdx.x;
    int stride = gridDim.x * 256;
    for (int i = i0; i < E; i += stride) {
        int d = dst[i];
        int s = src[i];
        int p = atomicAdd(&cur[d], 1);
        csr[p] = s;
    }
}

#define SR 40

// ---------------- mean aggregation over x16 (256 B rows, proven r6/r7) ------
__global__ __launch_bounds__(256) void aggF(
    const unsigned short* __restrict__ tab, const int* __restrict__ csr,
    const int* __restrict__ start, const int* __restrict__ deg,
    unsigned short* __restrict__ outm, int n) {
    int gid = blockIdx.x * blockDim.x + threadIdx.x;
    int wave = gid >> 6, lane = gid & 63;
    int sub = lane >> 4, fl = lane & 15;
    int node = wave * 4 + sub;
    if (node >= n) return;
    int s = start[node], d = deg[node];
    float4 A0 = {0.f, 0.f, 0.f, 0.f}, A1 = {0.f, 0.f, 0.f, 0.f};
    int j = 0;
    if (d >= 4) {
        int i0 = csr[s], i1 = csr[s + 1], i2 = csr[s + 2], i3 = csr[s + 3];
        for (; j + 8 <= d; j += 4) {
            int n0 = csr[s + j + 4], n1 = csr[s + j + 5];
            int n2 = csr[s + j + 6], n3 = csr[s + j + 7];
            uint4 r0 = ((const uint4*)(tab + (size_t)i0 * 128))[fl];
            uint4 r1 = ((const uint4*)(tab + (size_t)i1 * 128))[fl];
            uint4 r2 = ((const uint4*)(tab + (size_t)i2 * 128))[fl];
            uint4 r3 = ((const uint4*)(tab + (size_t)i3 * 128))[fl];
            acc8(r0, A0, A1); acc8(r1, A0, A1);
            acc8(r2, A0, A1); acc8(r3, A0, A1);
            i0 = n0; i1 = n1; i2 = n2; i3 = n3;
        }
        {
            uint4 r0 = ((const uint4*)(tab + (size_t)i0 * 128))[fl];
            uint4 r1 = ((const uint4*)(tab + (size_t)i1 * 128))[fl];
            uint4 r2 = ((const uint4*)(tab + (size_t)i2 * 128))[fl];
            uint4 r3 = ((const uint4*)(tab + (size_t)i3 * 128))[fl];
            acc8(r0, A0, A1); acc8(r1, A0, A1);
            acc8(r2, A0, A1); acc8(r3, A0, A1);
            j += 4;
        }
    }
    for (; j < d; ++j)
        acc8(((const uint4*)(tab + (size_t)csr[s + j] * 128))[fl], A0, A1);
    float inv = 1.0f / (float)max(d, 1);
    __half2 h0 = __floats2half2_rn(A0.x * inv, A0.y * inv);
    __half2 h1 = __floats2half2_rn(A0.z * inv, A0.w * inv);
    __half2 h2 = __floats2half2_rn(A1.x * inv, A1.y * inv);
    __half2 h3 = __floats2half2_rn(A1.z * inv, A1.w * inv);
    uint4 w;
    w.x = *(unsigned int*)&h0;
    w.y = *(unsigned int*)&h1;
    w.z = *(unsigned int*)&h2;
    w.w = *(unsigned int*)&h3;
    *(uint4*)&outm[(size_t)node * 128 + fl * 8] = w;
}

// ---------------- fused layer-1 + layer-2 GEMM, 20 KB LDS (r11 proven) ------
// (256,4): r12 proved (256,8) caps unified VGPR+AGPR at 64 -> massive spill
// (FETCH 26->120 MB, dur 62->143 us). 4 blocks/CU is this kernel's floor.
__global__ __launch_bounds__(256, 4) void fused12(
    const unsigned short* __restrict__ X, const unsigned short* __restrict__ XM,
    const unsigned short* __restrict__ W0H, const unsigned short* __restrict__ W0L,
    const unsigned short* __restrict__ W1H, const unsigned short* __restrict__ W1L,
    const float* __restrict__ b1,
    const unsigned short* __restrict__ W2aH, const unsigned short* __restrict__ W2aL,
    const unsigned short* __restrict__ W2bH, const unsigned short* __restrict__ W2bL,
    const float* __restrict__ b2,
    unsigned short* __restrict__ p16, float* __restrict__ outF, int n) {
    constexpr int CT = 2;
    __shared__ unsigned short lds[4 * 64 * SR];  // 20480 B
    unsigned short* hi0 = lds;
    unsigned short* hi1 = lds + 64 * SR;
    unsigned short* lo0 = lds + 2 * 64 * SR;
    unsigned short* lo1 = lds + 3 * 64 * SR;

    int t = threadIdx.x;
    int wv = t >> 6, l = t & 63, q = l >> 4, nl = l & 15;
    int node0 = blockIdx.x * 64;
    int sn = t >> 2, q4 = t & 3;
    int gn = min(node0 + sn, n - 1);
    int sbase = sn * SR + q4 * 8;

    // global loads first (longest latency)
    bf16x8 xr[4], s1r[4];
    {
        const unsigned short* p = X + (size_t)gn * 128 + q4 * 8;
#pragma unroll
        for (int c = 0; c < 4; ++c) xr[c] = *(const bf16x8*)(p + c * 32);
        const unsigned short* pm = XM + (size_t)gn * 128 + q4 * 8;
#pragma unroll
        for (int c = 0; c < 4; ++c) s1r[c] = *(const bf16x8*)(pm + c * 32);
    }

    f32x4 acc[4][CT];
#pragma unroll
    for (int a = 0; a < 4; ++a)
#pragma unroll
        for (int b = 0; b < CT; ++b) acc[a][b] = (f32x4){0.f, 0.f, 0.f, 0.f};

    bf16x8 whA[CT], wlA[CT], whB[CT], wlB[CT];
    int wcX = wv * 32;

#define LOAD_W(AH, AL, WHp, WLp, CC)                                       \
    {                                                                      \
        _Pragma("unroll") for (int uu = 0; uu < CT; ++uu) {                \
            int wb = (wcX + uu * 16 + nl) * 128 + (CC) * 32 + q * 8;       \
            AH[uu] = *(const bf16x8*)&(WHp)[wb];                           \
            AL[uu] = *(const bf16x8*)&(WLp)[wb];                           \
        }                                                                  \
    }

#define STAGE_CHUNK(HP, LP, RAW)                                           \
    {                                                                      \
        bf16x8 _hi, _lo;                                                   \
        split8h(RAW, _hi, _lo);                                            \
        *(bf16x8*)&(HP)[sbase] = _hi;                                      \
        *(bf16x8*)&(LP)[sbase] = _lo;                                      \
    }

#define MFMA_CHUNK(HP, LP, WHR, WLR)                                       \
    {                                                                      \
        bf16x8 ah[4], al[4];                                               \
        _Pragma("unroll") for (int tt = 0; tt < 4; ++tt) {                 \
            int off = (tt * 16 + nl) * SR + q * 8;                         \
            ah[tt] = *(const bf16x8*)&(HP)[off];                           \
            al[tt] = *(const bf16x8*)&(LP)[off];                           \
        }                                                                  \
        _Pragma("unroll") for (int tt = 0; tt < 4; ++tt)                   \
            _Pragma("unroll") for (int uu = 0; uu < CT; ++uu) {            \
                f32x4 a = acc[tt][uu];                                     \
                a = mfma16(al[tt], WHR[uu], a);                            \
                a = mfma16(ah[tt], WLR[uu], a);                            \
                a = mfma16(ah[tt], WHR[uu], a);                            \
                acc[tt][uu] = a;                                           \
            }                                                              \
    }

// 2-buffer phase: write chunk c+1 while computing chunk c (distinct buffers
// between every pair of barriers -> race-free by construction)
#define PHASE(RSRC, WHp, WLp)                                              \
    LOAD_W(whA, wlA, WHp, WLp, 0);                                         \
    STAGE_CHUNK(hi0, lo0, RSRC[0]);                                        \
    __syncthreads();                                                       \
    LOAD_W(whB, wlB, WHp, WLp, 1);                                         \
    STAGE_CHUNK(hi1, lo1, RSRC[1]);                                        \
    MFMA_CHUNK(hi0, lo0, whA, wlA);                                        \
    __syncthreads();                                                       \
    LOAD_W(whA, wlA, WHp, WLp, 2);                                         \
    STAGE_CHUNK(hi0, lo0, RSRC[2]);                                        \
    MFMA_CHUNK(hi1, lo1, whB, wlB);                                        \
    __syncthreads();                                                       \
    LOAD_W(whB, wlB, WHp, WLp, 3);                                         \
    STAGE_CHUNK(hi1, lo1, RSRC[3]);                                        \
    MFMA_CHUNK(hi0, lo0, whA, wlA);                                        \
    __syncthreads();                                                       \
    MFMA_CHUNK(hi1, lo1, whB, wlB);                                        \
    __syncthreads();

    PHASE(xr, W0H, W0L);    // acc += x @ Wr1
    PHASE(s1r, W1H, W1L);   // acc += xm @ Wl1

    // ---- h = relu(acc + b1) -> fp16 transpose buffer ----
    unsigned short* tb = lds;  // 64 x 136 = 8704 ushorts <= 10240 avail
#pragma unroll
    for (int uu = 0; uu < CT; ++uu) {
        int col = wcX + uu * 16 + nl;
        float bv = b1[col];
#pragma unroll
        for (int tt = 0; tt < 4; ++tt)
#pragma unroll
            for (int r = 0; r < 4; ++r) {
                float vv = fmaxf(acc[tt][uu][r] + bv, 0.f);
                tb[(tt * 16 + q * 4 + r) * 136 + col] =
                    __half_as_ushort(__float2half_rn(vv));
            }
    }
    __syncthreads();
    bf16x8 hreg[4];
    {
        const unsigned short* sp = tb + sn * 136 + q4 * 8;
#pragma unroll
        for (int c = 0; c < 4; ++c) hreg[c] = *(const bf16x8*)(sp + c * 32);
    }
    __syncthreads();  // tb reads done; lds free for phase-2 staging

    // ---- phase 2: acc = h @ W2[ysel] ----
#pragma unroll
    for (int a = 0; a < 4; ++a)
#pragma unroll
        for (int b = 0; b < CT; ++b) acc[a][b] = (f32x4){0.f, 0.f, 0.f, 0.f};
    int ysel = wv >> 1;
    wcX = (wv & 1) * 32;
    const unsigned short* W2H = ysel ? W2bH : W2aH;
    const unsigned short* W2L = ysel ? W2bL : W2aL;
    PHASE(hreg, W2H, W2L);

#undef PHASE
#undef MFMA_CHUNK
#undef STAGE_CHUNK
#undef LOAD_W

    // ---- epilogue: out direct-stored (64 B-contiguous groups), p16 via LDS -
    if (ysel) {
#pragma unroll
        for (int uu = 0; uu < CT; ++uu) {
            int col = wcX + uu * 16 + nl;
            float bv = b2[col];
#pragma unroll
            for (int tt = 0; tt < 4; ++tt)
#pragma unroll
                for (int r = 0; r < 4; ++r) {
                    int node = node0 + tt * 16 + q * 4 + r;
                    if (node < n) outF[(size_t)node * 64 + col] = acc[tt][uu][r] + bv;
                }
        }
    } else {
        unsigned short* tbu = lds;  // 64 x 72 = 4608 ushorts
#pragma unroll
        for (int uu = 0; uu < CT; ++uu) {
            int col = wcX + uu * 16 + nl;
#pragma unroll
            for (int tt = 0; tt < 4; ++tt)
#pragma unroll
                for (int r = 0; r < 4; ++r)
                    tbu[(tt * 16 + q * 4 + r) * 72 + col] =
                        __half_as_ushort(__float2half_rn(acc[tt][uu][r]));
        }
    }
    __syncthreads();
    {
        int node = node0 + sn;
        if (node < n) {
            const unsigned short* spu = lds + sn * 72 + q4 * 16;
            unsigned short* dpu = p16 + (size_t)node * 64 + q4 * 16;
            *(bf16x8*)dpu = *(const bf16x8*)spu;
            *(bf16x8*)(dpu + 8) = *(const bf16x8*)(spu + 8);
        }
    }
}

// ---------------- layer-2 aggregation: gather p16, out += mean (unroll-8) ---
__global__ __launch_bounds__(256) void aggP(
    const unsigned short* __restrict__ tab, const int* __restrict__ csr,
    const int* __restrict__ start, const int* __restrict__ deg,
    float* __restrict__ outF, int n) {
    int gid = blockIdx.x * blockDim.x + threadIdx.x;
    int wave = gid >> 6, lane = gid & 63;
    int sub = lane >> 4, fl = lane & 15;
    int node = wave * 4 + sub;
    if (node >= n) return;
    int s = start[node], d = deg[node];
    float4 A = {0.f, 0.f, 0.f, 0.f};
    int j = 0;
    if (d >= 8) {
        int idx[8];
#pragma unroll
        for (int k = 0; k < 8; ++k) idx[k] = csr[s + k];
        for (; j + 16 <= d; j += 8) {
            uint2 rr[8];
#pragma unroll
            for (int k = 0; k < 8; ++k)
                rr[k] = ((const uint2*)(tab + (size_t)idx[k] * 64))[fl];
#pragma unroll
            for (int k = 0; k < 8; ++k) idx[k] = csr[s + j + 8 + k];
#pragma unroll
            for (int k = 0; k < 8; ++k) acc4(rr[k], A);
        }
        {
            uint2 rr[8];
#pragma unroll
            for (int k = 0; k < 8; ++k)
                rr[k] = ((const uint2*)(tab + (size_t)idx[k] * 64))[fl];
#pragma unroll
            for (int k = 0; k < 8; ++k) acc4(rr[k], A);
            j += 8;
        }
    }
    for (; j < d; ++j)
        acc4(((const uint2*)(tab + (size_t)csr[s + j] * 64))[fl], A);
    float inv = 1.0f / (float)max(d, 1);
    float* op = outF + (size_t)node * 64 + fl * 4;
    float4 cur = *(float4*)op;
    cur.x += A.x * inv;
    cur.y += A.y * inv;
    cur.z += A.z * inv;
    cur.w += A.w * inv;
    *(float4*)op = cur;
}

// ---------------- launch ----------------

extern "C" void kernel_launch(void* const* d_in, const int* in_sizes, int n_in,
                              void* d_out, int out_size, void* d_ws, size_t ws_size,
                              hipStream_t stream) {
    const float* x   = (const float*)d_in[0];
    const int*   ei  = (const int*)d_in[1];
    const float* Wl1 = (const float*)d_in[2];
    const float* Wr1 = (const float*)d_in[3];
    const float* b1  = (const float*)d_in[4];
    const float* Wl2 = (const float*)d_in[5];
    const float* Wr2 = (const float*)d_in[6];
    const float* b2  = (const float*)d_in[7];
    float* out = (float*)d_out;

    int Nn = in_sizes[0] / 128;
    int E  = in_sizes[1] / 2;
    const int* src = ei;
    const int* dst = ei + E;
    int nb = (Nn + 127) / 128;  // 782 <= 1024

    char* ws = (char*)d_ws;
    auto alloc = [&](size_t bytes) -> char* {
        char* pp = ws;
        ws += (bytes + 255) / 256 * 256;
        return pp;
    };
    int* bcnt   = (int*)alloc((size_t)nb * 4);
    int* boff   = (int*)alloc((size_t)nb * 4);
    int* cur    = (int*)alloc((size_t)Nn * 4);
    int* start  = (int*)alloc((size_t)Nn * 4);
    int* deg    = (int*)alloc((size_t)Nn * 4);
    int* csr    = (int*)alloc((size_t)E * 4);
    unsigned short* x16  = (unsigned short*)alloc((size_t)Nn * 128 * 2);
    unsigned short* xm16 = (unsigned short*)alloc((size_t)Nn * 128 * 2);
    unsigned short* p16  = (unsigned short*)alloc((size_t)Nn * 64 * 2);
    unsigned short* w1ah = (unsigned short*)alloc(128 * 128 * 2);
    unsigned short* w1al = (unsigned short*)alloc(128 * 128 * 2);
    unsigned short* w1bh = (unsigned short*)alloc(128 * 128 * 2);
    unsigned short* w1bl = (unsigned short*)alloc(128 * 128 * 2);
    unsigned short* w2ah = (unsigned short*)alloc(64 * 128 * 2);
    unsigned short* w2al = (unsigned short*)alloc(64 * 128 * 2);
    unsigned short* w2bh = (unsigned short*)alloc(64 * 128 * 2);
    unsigned short* w2bl = (unsigned short*)alloc(64 * 128 * 2);

    hipMemsetAsync(deg, 0, (size_t)Nn * 4, stream);

    int total8 = Nn * 16;
    int xb = (total8 + 255) / 256;
    int nchunks = 256;
    int chunk = (E + nchunks - 1) / nchunks;
    k_prep<<<192 + xb + nchunks, 256, 0, stream>>>(
        Wl1, Wr1, Wl2, Wr2,
        w1ah, w1al, w1bh, w1bl, w2ah, w2al, w2bh, w2bl,
        x, x16, dst, deg, E, chunk, xb, total8);

    k_bsum<<<nb, 128, 0, stream>>>(deg, bcnt, Nn);
    k_bscan<<<1, 1024, 0, stream>>>(bcnt, boff, nb);
    k_nscan<<<nb, 128, 0, stream>>>(deg, boff, start, cur, Nn);
    k_scatter<<<2048, 256, 0, stream>>>(src, dst, cur, csr, E);

    int gb = (Nn + 63) / 64;
    int ga = (Nn + 15) / 16;
    // layer 1 gather: xm = mean-agg(x)      [full-occupancy, proven]
    aggF<<<ga, 256, 0, stream>>>(x16, csr, start, deg, xm16, Nn);
    // fused layers: h = relu(xm@Wl1 + x@Wr1 + b1) in-LDS;
    //               p = h@Wl2, out = h@Wr2 + b2
    fused12<<<gb, 256, 0, stream>>>(x16, xm16,
                                    w1bh, w1bl, w1ah, w1al, b1,
                                    w2ah, w2al, w2bh, w2bl, b2,
                                    p16, out, Nn);
    // layer 2 gather: out += mean-agg(p)    [linearity]
    aggP<<<ga, 256, 0, stream>>>(p16, csr, start, deg, out, Nn);
}

// Round 14
// 308.917 us; speedup vs baseline: 1.5443x; 1.5443x over previous
//
#include <hip/hip_runtime.h>
#include <hip/hip_fp16.h>

typedef __attribute__((ext_vector_type(8))) short bf16x8;
typedef __attribute__((ext_vector_type(4))) float f32x4;

__device__ __forceinline__ f32x4 mfma16(bf16x8 a, bf16x8 b, f32x4 c) {
    return __builtin_amdgcn_mfma_f32_16x16x32_bf16(a, b, c, 0, 0, 0);
}

__device__ __forceinline__ unsigned short bf16_rte(float f) {
    unsigned int u = __float_as_uint(f);
    unsigned int r = (u + 0x7FFFu + ((u >> 16) & 1u)) >> 16;
    return (unsigned short)r;
}
__device__ __forceinline__ float bf16_f(unsigned short h) {
    return __uint_as_float(((unsigned int)h) << 16);
}

// split 8 fp16 values (bit-packed) into bf16 hi/lo (exact)
__device__ __forceinline__ void split8h(bf16x8 raw, bf16x8& hi, bf16x8& lo) {
#pragma unroll
    for (int j = 0; j < 8; ++j) {
        float f = __half2float(__ushort_as_half((unsigned short)raw[j]));
        unsigned short h = bf16_rte(f);
        hi[j] = (short)h;
        lo[j] = (short)bf16_rte(f - bf16_f(h));
    }
}

__device__ __forceinline__ void acc8(uint4 r, float4& A0, float4& A1) {
    float2 v0 = __half22float2(*(const __half2*)&r.x);
    float2 v1 = __half22float2(*(const __half2*)&r.y);
    float2 v2 = __half22float2(*(const __half2*)&r.z);
    float2 v3 = __half22float2(*(const __half2*)&r.w);
    A0.x += v0.x; A0.y += v0.y; A0.z += v1.x; A0.w += v1.y;
    A1.x += v2.x; A1.y += v2.y; A1.z += v3.x; A1.w += v3.y;
}

__device__ __forceinline__ void acc4(uint2 r, float4& A) {
    float2 v0 = __half22float2(*(const __half2*)&r.x);
    float2 v1 = __half22float2(*(const __half2*)&r.y);
    A.x += v0.x; A.y += v0.y; A.z += v1.x; A.w += v1.y;
}

#define MAXNB 1024

// ---------------- fused prep: wconv + xconv + bcount (bcnt pre-zeroed) ------
__global__ __launch_bounds__(256) void k_prep(
    const float* __restrict__ Wl1, const float* __restrict__ Wr1,
    const float* __restrict__ Wl2, const float* __restrict__ Wr2,
    unsigned short* __restrict__ w1ah, unsigned short* __restrict__ w1al,
    unsigned short* __restrict__ w1bh, unsigned short* __restrict__ w1bl,
    unsigned short* __restrict__ w2ah, unsigned short* __restrict__ w2al,
    unsigned short* __restrict__ w2bh, unsigned short* __restrict__ w2bl,
    const float* __restrict__ x, unsigned short* __restrict__ x16,
    const int* __restrict__ dst, int* __restrict__ bcnt,
    int E, int chunk, int xb, int nb, int total8) {
    __shared__ int hh[MAXNB];
    int b = blockIdx.x;
    int t = threadIdx.x;
    if (b < 192) {  // weight conversion: 64+64+32+32 blocks
        const float* W;
        unsigned short *hi, *lo;
        int F, e;
        if (b < 64)       { W = Wl1; hi = w1ah; lo = w1al; F = 128; e = b * 256 + t; }
        else if (b < 128) { W = Wr1; hi = w1bh; lo = w1bl; F = 128; e = (b - 64) * 256 + t; }
        else if (b < 160) { W = Wl2; hi = w2ah; lo = w2al; F = 64;  e = (b - 128) * 256 + t; }
        else              { W = Wr2; hi = w2bh; lo = w2bl; F = 64;  e = (b - 160) * 256 + t; }
        if (e >= 128 * F) return;
        int col = e >> 7, k = e & 127;
        float v = W[(size_t)k * F + col];
        unsigned short h = bf16_rte(v);
        hi[e] = h;
        lo[e] = bf16_rte(v - bf16_f(h));
    } else if (b < 192 + xb) {  // x fp32 -> fp16 table
        int i = (b - 192) * 256 + t;
        if (i >= total8) return;
        const float4* xp = (const float4*)x + (size_t)i * 2;
        float4 a = xp[0], bb = xp[1];
        bf16x8 o;
        o[0] = (short)__half_as_ushort(__float2half_rn(a.x));
        o[1] = (short)__half_as_ushort(__float2half_rn(a.y));
        o[2] = (short)__half_as_ushort(__float2half_rn(a.z));
        o[3] = (short)__half_as_ushort(__float2half_rn(a.w));
        o[4] = (short)__half_as_ushort(__float2half_rn(bb.x));
        o[5] = (short)__half_as_ushort(__float2half_rn(bb.y));
        o[6] = (short)__half_as_ushort(__float2half_rn(bb.z));
        o[7] = (short)__half_as_ushort(__float2half_rn(bb.w));
        *(bf16x8*)&x16[(size_t)i * 8] = o;
    } else {  // bucket count (two-level histogram), 256 chunks (r9 proven)
        int cb = b - 192 - xb;
        for (int i = t; i < nb; i += 256) hh[i] = 0;
        __syncthreads();
        int base = cb * chunk;
        int end = min(base + chunk, E);
        for (int i = base + t; i < end; i += 256) atomicAdd(&hh[dst[i] >> 7], 1);
        __syncthreads();
        for (int i = t; i < nb; i += 256)
            if (hh[i]) atomicAdd(&bcnt[i], hh[i]);
    }
}

// ---------------- bucketed CSR build (r11 proven; wide blocks r14) ----------

__global__ void k_bscan(const int* __restrict__ bcnt, int* __restrict__ boff,
                        int* __restrict__ bcur, int nb) {
    __shared__ int sh[1024];
    int t = threadIdx.x;
    int v = (t < nb) ? bcnt[t] : 0;
    sh[t] = v;
    __syncthreads();
    for (int off = 1; off < 1024; off <<= 1) {
        int u = (t >= off) ? sh[t - off] : 0;
        __syncthreads();
        sh[t] += u;
        __syncthreads();
    }
    if (t < nb) {
        int ex = sh[t] - v;
        boff[t] = ex;
        bcur[t] = ex;
    }
}

// pair word = (dst & 127) << 25 | src   (src < 2^25; N = 100000 < 33.5M)
// r14: 1024 threads/block (was 256). Same 256 blocks -> per-block histogram
// fixed cost unchanged (r10 lesson), but 4x streaming waves (16 waves/CU).
__global__ __launch_bounds__(1024) void k_bscatter(
    const int* __restrict__ src, const int* __restrict__ dst,
    int* __restrict__ bcur, unsigned int* __restrict__ pairs,
    int E, int chunk, int nb) {
    __shared__ int h[MAXNB];
    __shared__ int curs[MAXNB];
    int t = threadIdx.x;
    for (int i = t; i < nb; i += 1024) h[i] = 0;
    __syncthreads();
    int base = blockIdx.x * chunk;
    int end = min(base + chunk, E);
    for (int i = base + t; i < end; i += 1024) atomicAdd(&h[dst[i] >> 7], 1);
    __syncthreads();
    for (int i = t; i < nb; i += 1024)
        curs[i] = h[i] ? atomicAdd(&bcur[i], h[i]) : 0;
    __syncthreads();
    for (int i = base + t; i < end; i += 1024) {
        int d = dst[i];
        int p = atomicAdd(&curs[d >> 7], 1);
        pairs[p] = ((unsigned int)(d & 127) << 25) | (unsigned int)src[i];
    }
}

// r14: 512 threads/block (edge loops stride 512; 128-wide scan unchanged).
__global__ __launch_bounds__(512) void k_build(
    const unsigned int* __restrict__ pairs, const int* __restrict__ boff,
    int* __restrict__ csr, int* __restrict__ start, int* __restrict__ deg,
    int n, int nb, int E) {
    __shared__ int scnt[128];
    __shared__ int soff[128];
    __shared__ int cur[128];
    int b = blockIdx.x;
    int t = threadIdx.x;
    int base = boff[b];
    int end = (b + 1 < nb) ? boff[b + 1] : E;
    if (t < 128) scnt[t] = 0;
    __syncthreads();
    for (int i = base + t; i < end; i += 512) {
        unsigned int e = pairs[i];
        atomicAdd(&scnt[e >> 25], 1);
    }
    __syncthreads();
    if (t < 128) soff[t] = scnt[t];
    __syncthreads();
    for (int off = 1; off < 128; off <<= 1) {
        int val = 0;
        if (t < 128 && t >= off) val = soff[t - off];
        __syncthreads();
        if (t < 128) soff[t] += val;
        __syncthreads();
    }
    if (t < 128) {
        int c = scnt[t];
        int ex = soff[t] - c;
        int node = b * 128 + t;
        if (node < n) {
            start[node] = base + ex;
            deg[node] = c;
        }
        cur[t] = base + ex;
    }
    __syncthreads();
    for (int i = base + t; i < end; i += 512) {
        unsigned int e = pairs[i];
        int p = atomicAdd(&cur[e >> 25], 1);
        csr[p] = (int)(e & 0x1FFFFFFu);
    }
}

#define SR 40

// ---------------- mean aggregation over x16 (256 B rows, proven r6/r7) ------
__global__ __launch_bounds__(256) void aggF(
    const unsigned short* __restrict__ tab, const int* __restrict__ csr,
    const int* __restrict__ start, const int* __restrict__ deg,
    unsigned short* __restrict__ outm, int n) {
    int gid = blockIdx.x * blockDim.x + threadIdx.x;
    int wave = gid >> 6, lane = gid & 63;
    int sub = lane >> 4, fl = lane & 15;
    int node = wave * 4 + sub;
    if (node >= n) return;
    int s = start[node], d = deg[node];
    float4 A0 = {0.f, 0.f, 0.f, 0.f}, A1 = {0.f, 0.f, 0.f, 0.f};
    int j = 0;
    if (d >= 4) {
        int i0 = csr[s], i1 = csr[s + 1], i2 = csr[s + 2], i3 = csr[s + 3];
        for (; j + 8 <= d; j += 4) {
            int n0 = csr[s + j + 4], n1 = csr[s + j + 5];
            int n2 = csr[s + j + 6], n3 = csr[s + j + 7];
            uint4 r0 = ((const uint4*)(tab + (size_t)i0 * 128))[fl];
            uint4 r1 = ((const uint4*)(tab + (size_t)i1 * 128))[fl];
            uint4 r2 = ((const uint4*)(tab + (size_t)i2 * 128))[fl];
            uint4 r3 = ((const uint4*)(tab + (size_t)i3 * 128))[fl];
            acc8(r0, A0, A1); acc8(r1, A0, A1);
            acc8(r2, A0, A1); acc8(r3, A0, A1);
            i0 = n0; i1 = n1; i2 = n2; i3 = n3;
        }
        {
            uint4 r0 = ((const uint4*)(tab + (size_t)i0 * 128))[fl];
            uint4 r1 = ((const uint4*)(tab + (size_t)i1 * 128))[fl];
            uint4 r2 = ((const uint4*)(tab + (size_t)i2 * 128))[fl];
            uint4 r3 = ((const uint4*)(tab + (size_t)i3 * 128))[fl];
            acc8(r0, A0, A1); acc8(r1, A0, A1);
            acc8(r2, A0, A1); acc8(r3, A0, A1);
            j += 4;
        }
    }
    for (; j < d; ++j)
        acc8(((const uint4*)(tab + (size_t)csr[s + j] * 128))[fl], A0, A1);
    float inv = 1.0f / (float)max(d, 1);
    __half2 h0 = __floats2half2_rn(A0.x * inv, A0.y * inv);
    __half2 h1 = __floats2half2_rn(A0.z * inv, A0.w * inv);
    __half2 h2 = __floats2half2_rn(A1.x * inv, A1.y * inv);
    __half2 h3 = __floats2half2_rn(A1.z * inv, A1.w * inv);
    uint4 w;
    w.x = *(unsigned int*)&h0;
    w.y = *(unsigned int*)&h1;
    w.z = *(unsigned int*)&h2;
    w.w = *(unsigned int*)&h3;
    *(uint4*)&outm[(size_t)node * 128 + fl * 8] = w;
}

// ---------------- fused layer-1 + layer-2 GEMM, 20 KB LDS (r11 proven) ------
// (256,4): r12 proved (256,8) caps unified VGPR+AGPR at 64 -> massive spill.
__global__ __launch_bounds__(256, 4) void fused12(
    const unsigned short* __restrict__ X, const unsigned short* __restrict__ XM,
    const unsigned short* __restrict__ W0H, const unsigned short* __restrict__ W0L,
    const unsigned short* __restrict__ W1H, const unsigned short* __restrict__ W1L,
    const float* __restrict__ b1,
    const unsigned short* __restrict__ W2aH, const unsigned short* __restrict__ W2aL,
    const unsigned short* __restrict__ W2bH, const unsigned short* __restrict__ W2bL,
    const float* __restrict__ b2,
    unsigned short* __restrict__ p16, float* __restrict__ outF, int n) {
    constexpr int CT = 2;
    __shared__ unsigned short lds[4 * 64 * SR];  // 20480 B
    unsigned short* hi0 = lds;
    unsigned short* hi1 = lds + 64 * SR;
    unsigned short* lo0 = lds + 2 * 64 * SR;
    unsigned short* lo1 = lds + 3 * 64 * SR;

    int t = threadIdx.x;
    int wv = t >> 6, l = t & 63, q = l >> 4, nl = l & 15;
    int node0 = blockIdx.x * 64;
    int sn = t >> 2, q4 = t & 3;
    int gn = min(node0 + sn, n - 1);
    int sbase = sn * SR + q4 * 8;

    // global loads first (longest latency)
    bf16x8 xr[4], s1r[4];
    {
        const unsigned short* p = X + (size_t)gn * 128 + q4 * 8;
#pragma unroll
        for (int c = 0; c < 4; ++c) xr[c] = *(const bf16x8*)(p + c * 32);
        const unsigned short* pm = XM + (size_t)gn * 128 + q4 * 8;
#pragma unroll
        for (int c = 0; c < 4; ++c) s1r[c] = *(const bf16x8*)(pm + c * 32);
    }

    f32x4 acc[4][CT];
#pragma unroll
    for (int a = 0; a < 4; ++a)
#pragma unroll
        for (int b = 0; b < CT; ++b) acc[a][b] = (f32x4){0.f, 0.f, 0.f, 0.f};

    bf16x8 whA[CT], wlA[CT], whB[CT], wlB[CT];
    int wcX = wv * 32;

#define LOAD_W(AH, AL, WHp, WLp, CC)                                       \
    {                                                                      \
        _Pragma("unroll") for (int uu = 0; uu < CT; ++uu) {                \
            int wb = (wcX + uu * 16 + nl) * 128 + (CC) * 32 + q * 8;       \
            AH[uu] = *(const bf16x8*)&(WHp)[wb];                           \
            AL[uu] = *(const bf16x8*)&(WLp)[wb];                           \
        }                                                                  \
    }

#define STAGE_CHUNK(HP, LP, RAW)                                           \
    {                                                                      \
        bf16x8 _hi, _lo;                                                   \
        split8h(RAW, _hi, _lo);                                            \
        *(bf16x8*)&(HP)[sbase] = _hi;                                      \
        *(bf16x8*)&(LP)[sbase] = _lo;                                      \
    }

#define MFMA_CHUNK(HP, LP, WHR, WLR)                                       \
    {                                                                      \
        bf16x8 ah[4], al[4];                                               \
        _Pragma("unroll") for (int tt = 0; tt < 4; ++tt) {                 \
            int off = (tt * 16 + nl) * SR + q * 8;                         \
            ah[tt] = *(const bf16x8*)&(HP)[off];                           \
            al[tt] = *(const bf16x8*)&(LP)[off];                           \
        }                                                                  \
        _Pragma("unroll") for (int tt = 0; tt < 4; ++tt)                   \
            _Pragma("unroll") for (int uu = 0; uu < CT; ++uu) {            \
                f32x4 a = acc[tt][uu];                                     \
                a = mfma16(al[tt], WHR[uu], a);                            \
                a = mfma16(ah[tt], WLR[uu], a);                            \
                a = mfma16(ah[tt], WHR[uu], a);                            \
                acc[tt][uu] = a;                                           \
            }                                                              \
    }

// 2-buffer phase: write chunk c+1 while computing chunk c (distinct buffers
// between every pair of barriers -> race-free by construction)
#define PHASE(RSRC, WHp, WLp)                                              \
    LOAD_W(whA, wlA, WHp, WLp, 0);                                         \
    STAGE_CHUNK(hi0, lo0, RSRC[0]);                                        \
    __syncthreads();                                                       \
    LOAD_W(whB, wlB, WHp, WLp, 1);                                         \
    STAGE_CHUNK(hi1, lo1, RSRC[1]);                                        \
    MFMA_CHUNK(hi0, lo0, whA, wlA);                                        \
    __syncthreads();                                                       \
    LOAD_W(whA, wlA, WHp, WLp, 2);                                         \
    STAGE_CHUNK(hi0, lo0, RSRC[2]);                                        \
    MFMA_CHUNK(hi1, lo1, whB, wlB);                                        \
    __syncthreads();                                                       \
    LOAD_W(whB, wlB, WHp, WLp, 3);                                         \
    STAGE_CHUNK(hi1, lo1, RSRC[3]);                                        \
    MFMA_CHUNK(hi0, lo0, whA, wlA);                                        \
    __syncthreads();                                                       \
    MFMA_CHUNK(hi1, lo1, whB, wlB);                                        \
    __syncthreads();

    PHASE(xr, W0H, W0L);    // acc += x @ Wr1
    PHASE(s1r, W1H, W1L);   // acc += xm @ Wl1

    // ---- h = relu(acc + b1) -> fp16 transpose buffer ----
    unsigned short* tb = lds;  // 64 x 136 = 8704 ushorts <= 10240 avail
#pragma unroll
    for (int uu = 0; uu < CT; ++uu) {
        int col = wcX + uu * 16 + nl;
        float bv = b1[col];
#pragma unroll
        for (int tt = 0; tt < 4; ++tt)
#pragma unroll
            for (int r = 0; r < 4; ++r) {
                float vv = fmaxf(acc[tt][uu][r] + bv, 0.f);
                tb[(tt * 16 + q * 4 + r) * 136 + col] =
                    __half_as_ushort(__float2half_rn(vv));
            }
    }
    __syncthreads();
    bf16x8 hreg[4];
    {
        const unsigned short* sp = tb + sn * 136 + q4 * 8;
#pragma unroll
        for (int c = 0; c < 4; ++c) hreg[c] = *(const bf16x8*)(sp + c * 32);
    }
    __syncthreads();  // tb reads done; lds free for phase-2 staging

    // ---- phase 2: acc = h @ W2[ysel] ----
#pragma unroll
    for (int a = 0; a < 4; ++a)
#pragma unroll
        for (int b = 0; b < CT; ++b) acc[a][b] = (f32x4){0.f, 0.f, 0.f, 0.f};
    int ysel = wv >> 1;
    wcX = (wv & 1) * 32;
    const unsigned short* W2H = ysel ? W2bH : W2aH;
    const unsigned short* W2L = ysel ? W2bL : W2aL;
    PHASE(hreg, W2H, W2L);

#undef PHASE
#undef MFMA_CHUNK
#undef STAGE_CHUNK
#undef LOAD_W

    // ---- epilogue: out direct-stored (64 B-contiguous groups), p16 via LDS -
    if (ysel) {
#pragma unroll
        for (int uu = 0; uu < CT; ++uu) {
            int col = wcX + uu * 16 + nl;
            float bv = b2[col];
#pragma unroll
            for (int tt = 0; tt < 4; ++tt)
#pragma unroll
                for (int r = 0; r < 4; ++r) {
                    int node = node0 + tt * 16 + q * 4 + r;
                    if (node < n) outF[(size_t)node * 64 + col] = acc[tt][uu][r] + bv;
                }
        }
    } else {
        unsigned short* tbu = lds;  // 64 x 72 = 4608 ushorts
#pragma unroll
        for (int uu = 0; uu < CT; ++uu) {
            int col = wcX + uu * 16 + nl;
#pragma unroll
            for (int tt = 0; tt < 4; ++tt)
#pragma unroll
                for (int r = 0; r < 4; ++r)
                    tbu[(tt * 16 + q * 4 + r) * 72 + col] =
                        __half_as_ushort(__float2half_rn(acc[tt][uu][r]));
        }
    }
    __syncthreads();
    {
        int node = node0 + sn;
        if (node < n) {
            const unsigned short* spu = lds + sn * 72 + q4 * 16;
            unsigned short* dpu = p16 + (size_t)node * 64 + q4 * 16;
            *(bf16x8*)dpu = *(const bf16x8*)spu;
            *(bf16x8*)(dpu + 8) = *(const bf16x8*)(spu + 8);
        }
    }
}

// ---------------- layer-2 aggregation: gather p16, out += mean (unroll-8) ---
__global__ __launch_bounds__(256) void aggP(
    const unsigned short* __restrict__ tab, const int* __restrict__ csr,
    const int* __restrict__ start, const int* __restrict__ deg,
    float* __restrict__ outF, int n) {
    int gid = blockIdx.x * blockDim.x + threadIdx.x;
    int wave = gid >> 6, lane = gid & 63;
    int sub = lane >> 4, fl = lane & 15;
    int node = wave * 4 + sub;
    if (node >= n) return;
    int s = start[node], d = deg[node];
    float4 A = {0.f, 0.f, 0.f, 0.f};
    int j = 0;
    if (d >= 8) {
        int idx[8];
#pragma unroll
        for (int k = 0; k < 8; ++k) idx[k] = csr[s + k];
        for (; j + 16 <= d; j += 8) {
            uint2 rr[8];
#pragma unroll
            for (int k = 0; k < 8; ++k)
                rr[k] = ((const uint2*)(tab + (size_t)idx[k] * 64))[fl];
#pragma unroll
            for (int k = 0; k < 8; ++k) idx[k] = csr[s + j + 8 + k];
#pragma unroll
            for (int k = 0; k < 8; ++k) acc4(rr[k], A);
        }
        {
            uint2 rr[8];
#pragma unroll
            for (int k = 0; k < 8; ++k)
                rr[k] = ((const uint2*)(tab + (size_t)idx[k] * 64))[fl];
#pragma unroll
            for (int k = 0; k < 8; ++k) acc4(rr[k], A);
            j += 8;
        }
    }
    for (; j < d; ++j)
        acc4(((const uint2*)(tab + (size_t)csr[s + j] * 64))[fl], A);
    float inv = 1.0f / (float)max(d, 1);
    float* op = outF + (size_t)node * 64 + fl * 4;
    float4 cur = *(float4*)op;
    cur.x += A.x * inv;
    cur.y += A.y * inv;
    cur.z += A.z * inv;
    cur.w += A.w * inv;
    *(float4*)op = cur;
}

// ---------------- launch ----------------

extern "C" void kernel_launch(void* const* d_in, const int* in_sizes, int n_in,
                              void* d_out, int out_size, void* d_ws, size_t ws_size,
                              hipStream_t stream) {
    const float* x   = (const float*)d_in[0];
    const int*   ei  = (const int*)d_in[1];
    const float* Wl1 = (const float*)d_in[2];
    const float* Wr1 = (const float*)d_in[3];
    const float* b1  = (const float*)d_in[4];
    const float* Wl2 = (const float*)d_in[5];
    const float* Wr2 = (const float*)d_in[6];
    const float* b2  = (const float*)d_in[7];
    float* out = (float*)d_out;

    int Nn = in_sizes[0] / 128;
    int E  = in_sizes[1] / 2;
    const int* src = ei;
    const int* dst = ei + E;
    int nb = (Nn + 127) / 128;  // 782 <= MAXNB

    char* ws = (char*)d_ws;
    auto alloc = [&](size_t bytes) -> char* {
        char* pp = ws;
        ws += (bytes + 255) / 256 * 256;
        return pp;
    };
    int* bcnt   = (int*)alloc((size_t)nb * 4);
    int* boff   = (int*)alloc((size_t)nb * 4);
    int* bcur   = (int*)alloc((size_t)nb * 4);
    int* start  = (int*)alloc((size_t)Nn * 4);
    int* deg    = (int*)alloc((size_t)Nn * 4);
    int* csr    = (int*)alloc((size_t)E * 4);
    unsigned short* x16  = (unsigned short*)alloc((size_t)Nn * 128 * 2);
    unsigned short* xm16 = (unsigned short*)alloc((size_t)Nn * 128 * 2);
    unsigned short* p16  = (unsigned short*)alloc((size_t)Nn * 64 * 2);
    unsigned short* w1ah = (unsigned short*)alloc(128 * 128 * 2);
    unsigned short* w1al = (unsigned short*)alloc(128 * 128 * 2);
    unsigned short* w1bh = (unsigned short*)alloc(128 * 128 * 2);
    unsigned short* w1bl = (unsigned short*)alloc(128 * 128 * 2);
    unsigned short* w2ah = (unsigned short*)alloc(64 * 128 * 2);
    unsigned short* w2al = (unsigned short*)alloc(64 * 128 * 2);
    unsigned short* w2bh = (unsigned short*)alloc(64 * 128 * 2);
    unsigned short* w2bl = (unsigned short*)alloc(64 * 128 * 2);
    // pairs (6.4 MB packed) aliases p16 (12.8 MB): consumed by k_build before
    // fused12 writes p16
    unsigned int* pairs = (unsigned int*)p16;

    hipMemsetAsync(bcnt, 0, (size_t)nb * 4, stream);

    int total8 = Nn * 16;
    int xb = (total8 + 255) / 256;
    int nchunks = 256;  // r9-proven; 1024 regressed (per-block histogram cost)
    int chunk = (E + nchunks - 1) / nchunks;
    k_prep<<<192 + xb + nchunks, 256, 0, stream>>>(
        Wl1, Wr1, Wl2, Wr2,
        w1ah, w1al, w1bh, w1bl, w2ah, w2al, w2bh, w2bl,
        x, x16, dst, bcnt, E, chunk, xb, nb, total8);

    k_bscan<<<1, 1024, 0, stream>>>(bcnt, boff, bcur, nb);
    k_bscatter<<<nchunks, 1024, 0, stream>>>(src, dst, bcur, pairs, E, chunk, nb);
    k_build<<<nb, 512, 0, stream>>>(pairs, boff, csr, start, deg, Nn, nb, E);

    int gb = (Nn + 63) / 64;
    int ga = (Nn + 15) / 16;
    // layer 1 gather: xm = mean-agg(x)      [full-occupancy, proven]
    aggF<<<ga, 256, 0, stream>>>(x16, csr, start, deg, xm16, Nn);
    // fused layers: h = relu(xm@Wl1 + x@Wr1 + b1) in-LDS;
    //               p = h@Wl2, out = h@Wr2 + b2
    fused12<<<gb, 256, 0, stream>>>(x16, xm16,
                                    w1bh, w1bl, w1ah, w1al, b1,
                                    w2ah, w2al, w2bh, w2bl, b2,
                                    p16, out, Nn);
    // layer 2 gather: out += mean-agg(p)    [linearity]
    aggP<<<ga, 256, 0, stream>>>(p16, csr, start, deg, out, Nn);
}